// Round 4
// baseline (206.552 us; speedup 1.0000x reference)
//
#include <hip/hip_runtime.h>
#include <hip/hip_bf16.h>
#include <stdint.h>

// Problem constants
#define Bq 8
#define Lq 2048
#define Dq 1024
#define Pq 4
#define Kq 4096          // D*P
#define LPAD 2056        // 3 zero rows + 2048 data + 5 slack, per batch
// GEMM tiling: 256x256, BK=64, 8-phase with cross-phase read-ahead
#define BM 256
#define BN 256
#define BK 64

typedef __attribute__((ext_vector_type(8))) short short8;   // 8 bf16 (4 VGPRs)
typedef __attribute__((ext_vector_type(4))) float f32x4;

__device__ __forceinline__ unsigned short f2bf(float f) {
  unsigned u = __float_as_uint(f);
  u += 0x7FFFu + ((u >> 16) & 1u);   // round-to-nearest-even
  return (unsigned short)(u >> 16);
}

__device__ __forceinline__ void gload_lds16(const void* g, void* l) {
  __builtin_amdgcn_global_load_lds(
      (const __attribute__((address_space(1))) void*)g,
      (__attribute__((address_space(3))) void*)l, 16, 0, 0);
}

// ---- merged prep: blocks [0,8224) do xp, blocks [8224,10272) do Wp ----
// xp[b][r][d] = (3 <= r < 2051) ? bf16(x[b][r-3][d]) : 0
// Wp[d][i*1024 + d'] = bf16(W[d][d'*4 + i])
__global__ void k_prep(const float* __restrict__ x, const float* __restrict__ W,
                       unsigned short* __restrict__ xp, unsigned short* __restrict__ Wp) {
  if (blockIdx.x < 8224u) {
    unsigned g = blockIdx.x * blockDim.x + threadIdx.x;
    unsigned base = g * 8;
    const unsigned total = (unsigned)Bq * LPAD * Dq;
    if (base >= total) return;
    unsigned t = base >> 10;            // b*LPAD + r
    unsigned b = t / LPAD;
    unsigned r = t - b * LPAD;
    unsigned d = base & 1023;
    short8 o;
    if (r >= 3 && r < 3 + Lq) {
      const float* s = x + ((size_t)b * Lq + (r - 3)) * Dq + d;
      float4 v0 = *(const float4*)(s);
      float4 v1 = *(const float4*)(s + 4);
      o[0] = (short)f2bf(v0.x); o[1] = (short)f2bf(v0.y);
      o[2] = (short)f2bf(v0.z); o[3] = (short)f2bf(v0.w);
      o[4] = (short)f2bf(v1.x); o[5] = (short)f2bf(v1.y);
      o[6] = (short)f2bf(v1.z); o[7] = (short)f2bf(v1.w);
    } else {
      o = (short8)0;
    }
    *(short8*)(xp + base) = o;
  } else {
    unsigned g = (blockIdx.x - 8224u) * blockDim.x + threadIdx.x;
    unsigned base = g * 8;
    unsigned d = base >> 12;
    unsigned rem = base & 4095;
    unsigned dp = rem >> 2;                               // even
    const float4* src = (const float4*)(W + base);
    float4 v0 = src[0];
    float4 v1 = src[1];
    float a0[4] = {v0.x, v0.y, v0.z, v0.w};
    float a1[4] = {v1.x, v1.y, v1.z, v1.w};
#pragma unroll
    for (int i = 0; i < 4; ++i) {
      unsigned packed = (unsigned)f2bf(a0[i]) | ((unsigned)f2bf(a1[i]) << 16);
      *(unsigned*)(Wp + (size_t)d * 4096 + (size_t)i * 1024 + dp) = packed;
    }
  }
}

// ================= 256x256 8-phase GEMM, cross-phase read-ahead =============
// C[m][n] = sum_k A[m][k]*Wp[n][k] + bias[n],  A[m][i*1024+d'] = xp[b][l+3-i][d']
//
// LDS (128 KiB): per dbuf(2): [Ah0 16K][Ah1 16K][Bh0 16K][Bh1 16K]
//   byte within 128B row: SWIZZLED  phys_c = log_c ^ ((r&7)<<4)
// 8 waves: wm = w>>2, wn = w&3. Tile quadrant order Q00,Q01,Q11,Q10.
// Fragment slots: aX/aY (32 VGPR each), bX/bY (16 each); B roles swap per tile.
// Phase p issues ds_reads for phase p+1 AFTER barrier1, then waits
// lgkmcnt(N_cur) -> only prev-phase reads gate the MFMA (already complete).
// sched_barrier(0x3F7) pins MFMA below the counted wait (rule #18).

#define VM6 asm volatile("s_waitcnt vmcnt(6)" ::: "memory")
#define VM4 asm volatile("s_waitcnt vmcnt(4)" ::: "memory")
#define VM0 asm volatile("s_waitcnt vmcnt(0)" ::: "memory")
#define LGKM(n) asm volatile("s_waitcnt lgkmcnt(" #n ")" ::: "memory")
#define SB_NOMFMA __builtin_amdgcn_sched_barrier(0x3F7)
#define BAR __builtin_amdgcn_s_barrier()

#define STAGE_A(buf, kt, h) do { \
    const int i_ = (kt) >> 4; const int d0_ = ((kt) & 15) << 6; \
    _Pragma("unroll") for (int q_ = 0; q_ < 2; ++q_) { \
      const unsigned short* src_ = xp + (((size_t)(aRowBase + q_ * 128 + (h) * 64 - i_)) << 10) + d0_ + clog; \
      gload_lds16(src_, lds + ((buf) << 16) + ((h) << 14) + (q_ << 13) + (tid << 4)); \
    } } while (0)

#define STAGE_B(buf, kt, h) do { \
    _Pragma("unroll") for (int q_ = 0; q_ < 2; ++q_) { \
      const unsigned short* src_ = Wp + (((size_t)(nBase0 + q_ * 128 + (h) * 32)) << 12) + ((kt) << 6) + clog; \
      gload_lds16(src_, lds + ((buf) << 16) + 32768 + ((h) << 14) + (q_ << 13) + (tid << 4)); \
    } } while (0)

#define READ_A(dst, buf, h) do { \
    _Pragma("unroll") for (int mi = 0; mi < 4; ++mi) \
    _Pragma("unroll") for (int kk = 0; kk < 2; ++kk) \
      dst[mi][kk] = *(const short8*)(lds + ((buf) << 16) + ((h) << 14) + aRowByte[mi] + colByte[kk]); \
  } while (0)

#define READ_B(dst, buf, h) do { \
    _Pragma("unroll") for (int ni = 0; ni < 2; ++ni) \
    _Pragma("unroll") for (int kk = 0; kk < 2; ++kk) \
      dst[ni][kk] = *(const short8*)(lds + ((buf) << 16) + 32768 + ((h) << 14) + bRowByte[ni] + colByte[kk]); \
  } while (0)

#define MFMAQ(mh, nh, A, Bv) do { \
    __builtin_amdgcn_s_setprio(1); \
    _Pragma("unroll") for (int mi = 0; mi < 4; ++mi) \
    _Pragma("unroll") for (int ni = 0; ni < 2; ++ni) \
    _Pragma("unroll") for (int kk = 0; kk < 2; ++kk) \
      acc[(mh) * 4 + mi][(nh) * 2 + ni] = __builtin_amdgcn_mfma_f32_16x16x32_bf16( \
          A[mi][kk], Bv[ni][kk], acc[(mh) * 4 + mi][(nh) * 2 + ni], 0, 0, 0); \
    __builtin_amdgcn_s_setprio(0); \
  } while (0)

__global__ void __launch_bounds__(512, 2)
k_gemm(const unsigned short* __restrict__ xp,
       const unsigned short* __restrict__ Wp,
       const float* __restrict__ bias,
       float* __restrict__ out) {
  __shared__ __attribute__((aligned(16))) unsigned char lds[131072];

  const int tid  = threadIdx.x;
  const int lane = tid & 63;
  const int w    = tid >> 6;       // 0..7
  const int wm   = w >> 2;         // 0..1
  const int wn   = w & 3;          // 0..3

  // bijective XCD swizzle (256 blocks): each XCD gets a contiguous
  // 8-mtile x 4-ntile chunk -> A fetched once per XCD.
  const int bid = blockIdx.x;
  const int swz = (bid & 7) * 32 + (bid >> 3);
  const int m0 = (swz >> 2) * BM;
  const int n0 = (swz & 3) * BN;
  const int b  = m0 >> 11;
  const int l0 = m0 & 2047;

  // ---- staging geometry (per thread) ----
  const int sr0 = tid >> 3;                                  // region row; issue q adds q*64
  const int clog = ((tid & 7) ^ (sr0 & 7)) << 3;             // pre-swizzled source elem offset
  const int aRowBase = b * LPAD + l0 + 3 + sr0;
  const int nBase0 = n0 + ((sr0 >> 5) << 6) + (sr0 & 31);

  // ---- ds_read geometry (per thread) ----
  int aRowByte[4], bRowByte[2], colByte[2];
#pragma unroll
  for (int mi = 0; mi < 4; ++mi) aRowByte[mi] = (wm * 64 + mi * 16 + (lane & 15)) << 7;
#pragma unroll
  for (int ni = 0; ni < 2; ++ni) bRowByte[ni] = (wn * 32 + ni * 16 + (lane & 15)) << 7;
#pragma unroll
  for (int kk = 0; kk < 2; ++kk)
    colByte[kk] = (kk * 64 + ((lane >> 4) << 4)) ^ ((lane & 7) << 4);

  f32x4 acc[8][4] = {};
  short8 aX[4][2], aY[4][2], bX[2][2], bY[2][2];

  // ---- prologue: stage tile0 fully + tile1 (Ah0,Bh1,Ah1); preload frags ----
  STAGE_A(0, 0, 0);
  STAGE_B(0, 0, 1);
  STAGE_A(0, 0, 1);
  STAGE_B(0, 0, 0);
  VM4;
  STAGE_A(1, 1, 0);
  STAGE_B(1, 1, 1);
  STAGE_A(1, 1, 1);
  VM6;                               // tile0 fully landed (per-wave)
  BAR;                               // all waves' tile0 landed
  READ_A(aX, 0, 0);                  // A0(t0)
  READ_B(bX, 0, 0);                  // B0(t0)   (ph1's LGKM(4) covers these)

  // ---- main loop: 31 iters, tiles T=2it (buf0), U=2it+1 (buf1) ----
#pragma unroll 1
  for (int it = 0; it < 31; ++it) {
    const int T = it * 2;
    // ph1: Q00(T) = aX,bX          reads: B1(T)->bY
    STAGE_B(1, T + 1, 0);
    BAR;
    READ_B(bY, 0, 1);
    LGKM(4); SB_NOMFMA;
    MFMAQ(0, 0, aX, bX);
    BAR;
    // ph2: Q01(T) = aX,bY          reads: A1(T)->aY
    STAGE_A(0, T + 2, 0);
    BAR;
    READ_A(aY, 0, 1);
    LGKM(8); SB_NOMFMA;
    MFMAQ(0, 1, aX, bY);
    BAR;
    // ph3: Q11(T) = aY,bY          reads: none
    STAGE_B(0, T + 2, 1);
    BAR;
    LGKM(0); SB_NOMFMA;
    MFMAQ(1, 1, aY, bY);
    BAR;
    // ph4: Q10(T) = aY,bX          reads: A0(U)->aX, B0(U)->bY   (U landed)
    STAGE_A(0, T + 2, 1);
    VM6;
    BAR;
    READ_A(aX, 1, 0);
    READ_B(bY, 1, 0);
    LGKM(12); SB_NOMFMA;
    MFMAQ(1, 0, aY, bX);
    BAR;
    // ph5: Q00(U) = aX,bY          reads: B1(U)->bX
    STAGE_B(0, T + 2, 0);
    BAR;
    READ_B(bX, 1, 1);
    LGKM(4); SB_NOMFMA;
    MFMAQ(0, 0, aX, bY);
    BAR;
    // ph6: Q01(U) = aX,bX          reads: A1(U)->aY
    STAGE_A(1, T + 3, 0);
    BAR;
    READ_A(aY, 1, 1);
    LGKM(8); SB_NOMFMA;
    MFMAQ(0, 1, aX, bX);
    BAR;
    // ph7: Q11(U) = aY,bX          reads: none
    STAGE_B(1, T + 3, 1);
    BAR;
    LGKM(0); SB_NOMFMA;
    MFMAQ(1, 1, aY, bX);
    BAR;
    // ph8: Q10(U) = aY,bY          reads: A0(T+2)->aX, B0(T+2)->bX  (T+2 landed)
    STAGE_A(1, T + 3, 1);
    VM6;
    BAR;
    READ_A(aX, 0, 0);
    READ_B(bX, 0, 0);
    LGKM(12); SB_NOMFMA;
    MFMAQ(1, 0, aY, bY);
    BAR;
  }

  // ---- epilogue: tiles 62 (buf0), 63 (buf1) ----
  // ph1e
  STAGE_B(1, 63, 0);
  BAR;
  READ_B(bY, 0, 1);
  LGKM(4); SB_NOMFMA;
  MFMAQ(0, 0, aX, bX);
  BAR;
  // ph2e
  READ_A(aY, 0, 1);
  LGKM(8); SB_NOMFMA;
  MFMAQ(0, 1, aX, bY);
  BAR;
  // ph3e
  LGKM(0); SB_NOMFMA;
  MFMAQ(1, 1, aY, bY);
  BAR;
  // ph4e: drain, then read tile63 frags
  VM0;
  BAR;
  READ_A(aX, 1, 0);
  READ_B(bY, 1, 0);
  LGKM(12); SB_NOMFMA;
  MFMAQ(1, 0, aY, bX);
  BAR;
  // ph5e
  READ_B(bX, 1, 1);
  LGKM(4); SB_NOMFMA;
  MFMAQ(0, 0, aX, bY);
  BAR;
  // ph6e
  READ_A(aY, 1, 1);
  LGKM(8); SB_NOMFMA;
  MFMAQ(0, 1, aX, bX);
  BAR;
  // ph7e
  LGKM(0); SB_NOMFMA;
  MFMAQ(1, 1, aY, bX);
  // ph8e
  LGKM(0); SB_NOMFMA;
  MFMAQ(1, 0, aY, bY);

  // ---- C write: col = lane&15, row = (lane>>4)*4 + reg ----
#pragma unroll
  for (int nig = 0; nig < 4; ++nig) {
    const int col = n0 + wn * 64 + nig * 16 + (lane & 15);
    const float bv = bias[col];
#pragma unroll
    for (int mig = 0; mig < 8; ++mig) {
      const int row0 = m0 + wm * 128 + mig * 16 + ((lane >> 4) << 2);
#pragma unroll
      for (int t2 = 0; t2 < 4; ++t2)
        out[(size_t)(row0 + t2) * Dq + col] = acc[mig][nig][t2] + bv;
    }
  }
}

// ---- slow-but-correct fallback if workspace is too small ----
__global__ void k_naive(const float* __restrict__ x, const float* __restrict__ W,
                        const float* __restrict__ bias, float* __restrict__ out) {
  size_t g = (size_t)blockIdx.x * blockDim.x + threadIdx.x;
  const size_t total = (size_t)Bq * Lq * Dq;
  if (g >= total) return;
  int d = (int)(g & 1023);
  int l = (int)((g >> 10) & 2047);
  int b = (int)(g >> 21);
  float s = bias[d];
  for (int i = 0; i < Pq; ++i) {
    if (l - i < 0) continue;
    const float* xr = x + ((size_t)b * Lq + (l - i)) * Dq;
    const float* wr = W + (size_t)d * Kq + i;
    float accv = 0.f;
    for (int dp = 0; dp < Dq; ++dp) accv += xr[dp] * wr[(size_t)dp * 4];
    s += accv;
  }
  out[g] = s;
}

extern "C" void kernel_launch(void* const* d_in, const int* in_sizes, int n_in,
                              void* d_out, int out_size, void* d_ws, size_t ws_size,
                              hipStream_t stream) {
  const float* x    = (const float*)d_in[0];
  const float* W    = (const float*)d_in[1];
  const float* bias = (const float*)d_in[2];
  float* out = (float*)d_out;

  const size_t WP_BYTES = (size_t)Dq * Kq * sizeof(unsigned short);        // 8 MiB
  const size_t XP_BYTES = (size_t)Bq * LPAD * Dq * sizeof(unsigned short); // ~33.7 MB

  if (ws_size < WP_BYTES + XP_BYTES) {
    const size_t total = (size_t)Bq * Lq * Dq;
    k_naive<<<(unsigned)((total + 255) / 256), 256, 0, stream>>>(x, W, bias, out);
    return;
  }

  unsigned short* Wp = (unsigned short*)d_ws;
  unsigned short* xp = (unsigned short*)((char*)d_ws + WP_BYTES);

  k_prep<<<10272, 256, 0, stream>>>(x, W, xp, Wp);
  k_gemm<<<dim3((Bq * Lq / BM) * (Dq / BN)), 512, 0, stream>>>(xp, Wp, bias, out);
}

// Round 5
// 135.299 us; speedup vs baseline: 1.5266x; 1.5266x over previous
//
#include <hip/hip_runtime.h>
#include <hip/hip_bf16.h>
#include <stdint.h>

// Problem constants
#define Bq 8
#define Lq 2048
#define Dq 1024
#define Pq 4
#define Kq 4096          // D*P
#define LPAD 2056        // 3 zero rows + 2048 data + 5 slack, per batch
// GEMM tiling: 256x256, BK=64, 8-phase, B-fragment persistence (24 reads/tile)
#define BM 256
#define BN 256
#define BK 64

typedef __attribute__((ext_vector_type(8))) short short8;   // 8 bf16 (4 VGPRs)
typedef __attribute__((ext_vector_type(4))) float f32x4;

__device__ __forceinline__ unsigned short f2bf(float f) {
  unsigned u = __float_as_uint(f);
  u += 0x7FFFu + ((u >> 16) & 1u);   // round-to-nearest-even
  return (unsigned short)(u >> 16);
}

__device__ __forceinline__ void gload_lds16(const void* g, void* l) {
  __builtin_amdgcn_global_load_lds(
      (const __attribute__((address_space(1))) void*)g,
      (__attribute__((address_space(3))) void*)l, 16, 0, 0);
}

// ---- merged prep: blocks [0,8224) do xp, blocks [8224,10272) do Wp ----
// xp[b][r][d] = (3 <= r < 2051) ? bf16(x[b][r-3][d]) : 0
// Wp[d][i*1024 + d'] = bf16(W[d][d'*4 + i])
__global__ void k_prep(const float* __restrict__ x, const float* __restrict__ W,
                       unsigned short* __restrict__ xp, unsigned short* __restrict__ Wp) {
  if (blockIdx.x < 8224u) {
    unsigned g = blockIdx.x * blockDim.x + threadIdx.x;
    unsigned base = g * 8;
    const unsigned total = (unsigned)Bq * LPAD * Dq;
    if (base >= total) return;
    unsigned t = base >> 10;            // b*LPAD + r
    unsigned b = t / LPAD;
    unsigned r = t - b * LPAD;
    unsigned d = base & 1023;
    short8 o;
    if (r >= 3 && r < 3 + Lq) {
      const float* s = x + ((size_t)b * Lq + (r - 3)) * Dq + d;
      float4 v0 = *(const float4*)(s);
      float4 v1 = *(const float4*)(s + 4);
      o[0] = (short)f2bf(v0.x); o[1] = (short)f2bf(v0.y);
      o[2] = (short)f2bf(v0.z); o[3] = (short)f2bf(v0.w);
      o[4] = (short)f2bf(v1.x); o[5] = (short)f2bf(v1.y);
      o[6] = (short)f2bf(v1.z); o[7] = (short)f2bf(v1.w);
    } else {
      o = (short8)0;
    }
    *(short8*)(xp + base) = o;
  } else {
    unsigned g = (blockIdx.x - 8224u) * blockDim.x + threadIdx.x;
    unsigned base = g * 8;
    unsigned d = base >> 12;
    unsigned rem = base & 4095;
    unsigned dp = rem >> 2;                               // even
    const float4* src = (const float4*)(W + base);
    float4 v0 = src[0];
    float4 v1 = src[1];
    float a0[4] = {v0.x, v0.y, v0.z, v0.w};
    float a1[4] = {v1.x, v1.y, v1.z, v1.w};
#pragma unroll
    for (int i = 0; i < 4; ++i) {
      unsigned packed = (unsigned)f2bf(a0[i]) | ((unsigned)f2bf(a1[i]) << 16);
      *(unsigned*)(Wp + (size_t)d * 4096 + (size_t)i * 1024 + dp) = packed;
    }
  }
}

// ================= 256x256 8-phase GEMM, B-persist (24 reads/tile) ==========
// C[m][n] = sum_k A[m][k]*Wp[n][k] + bias[n],  A[m][i*1024+d'] = xp[b][l+3-i][d']
// LDS (128 KiB): per dbuf(2): [Ah0 16K][Ah1 16K][Bh0 16K][Bh1 16K]
//   byte within 128B row: SWIZZLED  phys_c = log_c ^ ((r&7)<<4)
// 8 waves: wm = w>>2, wn = w&3. Quadrant order per tile: Q00,Q01,Q11,Q10.
// Frags: fa (A-half, overwritten mid-tile, 32 VGPR), bX=B0/bY=B1 (persist, 16+16).
// Reads per phase: {16,0,8,0} -> 24/tile = data floor. Stage schedule + vmcnt
// ledger identical to the verified R3 kernel (VM6 at ph4: tile U landed;
// VM6 at ph8: tile T+2 landed). 2 barriers/phase keep waves phase-locked,
// which the stage-vs-read hazard table relies on.

#define VM6 asm volatile("s_waitcnt vmcnt(6)" ::: "memory")
#define VM4 asm volatile("s_waitcnt vmcnt(4)" ::: "memory")
#define VM0 asm volatile("s_waitcnt vmcnt(0)" ::: "memory")
#define BAR __builtin_amdgcn_s_barrier()

#define STAGE_A(buf, kt, h) do { \
    const int i_ = (kt) >> 4; const int d0_ = ((kt) & 15) << 6; \
    _Pragma("unroll") for (int q_ = 0; q_ < 2; ++q_) { \
      const unsigned short* src_ = xp + (((size_t)(aRowBase + q_ * 128 + (h) * 64 - i_)) << 10) + d0_ + clog; \
      gload_lds16(src_, lds + ((buf) << 16) + ((h) << 14) + (q_ << 13) + (tid << 4)); \
    } } while (0)

#define STAGE_B(buf, kt, h) do { \
    _Pragma("unroll") for (int q_ = 0; q_ < 2; ++q_) { \
      const unsigned short* src_ = Wp + (((size_t)(nBase0 + q_ * 128 + (h) * 32)) << 12) + ((kt) << 6) + clog; \
      gload_lds16(src_, lds + ((buf) << 16) + 32768 + ((h) << 14) + (q_ << 13) + (tid << 4)); \
    } } while (0)

#define READ_A(dst, buf, h) do { \
    _Pragma("unroll") for (int mi = 0; mi < 4; ++mi) \
    _Pragma("unroll") for (int kk = 0; kk < 2; ++kk) \
      dst[mi][kk] = *(const short8*)(lds + ((buf) << 16) + ((h) << 14) + aRowByte[mi] + colByte[kk]); \
  } while (0)

#define READ_B(dst, buf, h) do { \
    _Pragma("unroll") for (int ni = 0; ni < 2; ++ni) \
    _Pragma("unroll") for (int kk = 0; kk < 2; ++kk) \
      dst[ni][kk] = *(const short8*)(lds + ((buf) << 16) + 32768 + ((h) << 14) + bRowByte[ni] + colByte[kk]); \
  } while (0)

#define MFMAQ(mh, nh, A, Bv) do { \
    __builtin_amdgcn_s_setprio(1); \
    _Pragma("unroll") for (int mi = 0; mi < 4; ++mi) \
    _Pragma("unroll") for (int ni = 0; ni < 2; ++ni) \
    _Pragma("unroll") for (int kk = 0; kk < 2; ++kk) \
      acc[(mh) * 4 + mi][(nh) * 2 + ni] = __builtin_amdgcn_mfma_f32_16x16x32_bf16( \
          A[mi][kk], Bv[ni][kk], acc[(mh) * 4 + mi][(nh) * 2 + ni], 0, 0, 0); \
    __builtin_amdgcn_s_setprio(0); \
  } while (0)

__global__ void __launch_bounds__(512, 2)
k_gemm(const unsigned short* __restrict__ xp,
       const unsigned short* __restrict__ Wp,
       const float* __restrict__ bias,
       float* __restrict__ out) {
  __shared__ __attribute__((aligned(16))) unsigned char lds[131072];

  const int tid  = threadIdx.x;
  const int lane = tid & 63;
  const int w    = tid >> 6;       // 0..7
  const int wm   = w >> 2;         // 0..1
  const int wn   = w & 3;          // 0..3

  // bijective XCD swizzle (256 blocks): each XCD gets a contiguous
  // 8-mtile x 4-ntile chunk -> A fetched once per XCD.
  const int bid = blockIdx.x;
  const int swz = (bid & 7) * 32 + (bid >> 3);
  const int m0 = (swz >> 2) * BM;
  const int n0 = (swz & 3) * BN;
  const int b  = m0 >> 11;
  const int l0 = m0 & 2047;

  // ---- staging geometry (per thread) ----
  const int sr0 = tid >> 3;                                  // region row; issue q adds q*64
  const int clog = ((tid & 7) ^ (sr0 & 7)) << 3;             // pre-swizzled source elem offset
  const int aRowBase = b * LPAD + l0 + 3 + sr0;
  const int nBase0 = n0 + ((sr0 >> 5) << 6) + (sr0 & 31);

  // ---- ds_read geometry (per thread) ----
  int aRowByte[4], bRowByte[2], colByte[2];
#pragma unroll
  for (int mi = 0; mi < 4; ++mi) aRowByte[mi] = (wm * 64 + mi * 16 + (lane & 15)) << 7;
#pragma unroll
  for (int ni = 0; ni < 2; ++ni) bRowByte[ni] = (wn * 32 + ni * 16 + (lane & 15)) << 7;
#pragma unroll
  for (int kk = 0; kk < 2; ++kk)
    colByte[kk] = (kk * 64 + ((lane >> 4) << 4)) ^ ((lane & 7) << 4);

  f32x4 acc[8][4] = {};
  short8 fa[4][2], bX[2][2], bY[2][2];

  // ---- prologue: stage tile0 fully + tile1 (Ah0,Bh1,Ah1) ----
  STAGE_A(0, 0, 0);
  STAGE_B(0, 0, 1);
  STAGE_A(0, 0, 1);
  STAGE_B(0, 0, 0);
  VM4;
  STAGE_A(1, 1, 0);
  STAGE_B(1, 1, 1);
  STAGE_A(1, 1, 1);
  VM6;                               // tile0 fully landed (per-wave)
  BAR;                               // all waves' tile0 landed

  // ---- main loop: 31 iters, tiles T=2it (buf0), U=2it+1 (buf1) ----
#pragma unroll 1
  for (int it = 0; it < 31; ++it) {
    const int T = it * 2;
    // ph1: Q00(T)=fa,bX   reads A0,B0,B1(T)  stage B0(U)
    READ_A(fa, 0, 0); READ_B(bX, 0, 0); READ_B(bY, 0, 1);
    STAGE_B(1, T + 1, 0);
    BAR; MFMAQ(0, 0, fa, bX); BAR;
    // ph2: Q01(T)=fa,bY   stage A0(T+2)
    STAGE_A(0, T + 2, 0);
    BAR; MFMAQ(0, 1, fa, bY); BAR;
    // ph3: Q11(T)=fa',bY  reads A1(T)        stage B1(T+2)
    READ_A(fa, 0, 1);
    STAGE_B(0, T + 2, 1);
    BAR; MFMAQ(1, 1, fa, bY); BAR;
    // ph4: Q10(T)=fa',bX  stage A1(T+2); VM6 -> tile U landed
    STAGE_A(0, T + 2, 1);
    VM6;
    BAR; MFMAQ(1, 0, fa, bX); BAR;
    // ph5: Q00(U)         reads A0,B0,B1(U)  stage B0(T+2)
    READ_A(fa, 1, 0); READ_B(bX, 1, 0); READ_B(bY, 1, 1);
    STAGE_B(0, T + 2, 0);
    BAR; MFMAQ(0, 0, fa, bX); BAR;
    // ph6: Q01(U)         stage A0(T+3)
    STAGE_A(1, T + 3, 0);
    BAR; MFMAQ(0, 1, fa, bY); BAR;
    // ph7: Q11(U)         reads A1(U)        stage B1(T+3)
    READ_A(fa, 1, 1);
    STAGE_B(1, T + 3, 1);
    BAR; MFMAQ(1, 1, fa, bY); BAR;
    // ph8: Q10(U)         stage A1(T+3); VM6 -> tile T+2 landed
    STAGE_A(1, T + 3, 1);
    VM6;
    BAR; MFMAQ(1, 0, fa, bX); BAR;
  }

  // ---- epilogue: tiles 62 (buf0), 63 (buf1) ----
  READ_A(fa, 0, 0); READ_B(bX, 0, 0); READ_B(bY, 0, 1);
  STAGE_B(1, 63, 0);                 // tile63 Bh0 (last missing piece)
  BAR; MFMAQ(0, 0, fa, bX); BAR;
  MFMAQ(0, 1, fa, bY);
  READ_A(fa, 0, 1);
  MFMAQ(1, 1, fa, bY);
  MFMAQ(1, 0, fa, bX);
  VM0;                               // tile63 landed (per-wave)
  BAR;                               // all waves' tile63 landed
  READ_A(fa, 1, 0); READ_B(bX, 1, 0); READ_B(bY, 1, 1);
  MFMAQ(0, 0, fa, bX);
  MFMAQ(0, 1, fa, bY);
  READ_A(fa, 1, 1);
  MFMAQ(1, 1, fa, bY);
  MFMAQ(1, 0, fa, bX);

  // ---- C write: col = lane&15, row = (lane>>4)*4 + reg ----
#pragma unroll
  for (int nig = 0; nig < 4; ++nig) {
    const int col = n0 + wn * 64 + nig * 16 + (lane & 15);
    const float bv = bias[col];
#pragma unroll
    for (int mig = 0; mig < 8; ++mig) {
      const int row0 = m0 + wm * 128 + mig * 16 + ((lane >> 4) << 2);
#pragma unroll
      for (int t2 = 0; t2 < 4; ++t2)
        out[(size_t)(row0 + t2) * Dq + col] = acc[mig][nig][t2] + bv;
    }
  }
}

// ---- slow-but-correct fallback if workspace is too small ----
__global__ void k_naive(const float* __restrict__ x, const float* __restrict__ W,
                        const float* __restrict__ bias, float* __restrict__ out) {
  size_t g = (size_t)blockIdx.x * blockDim.x + threadIdx.x;
  const size_t total = (size_t)Bq * Lq * Dq;
  if (g >= total) return;
  int d = (int)(g & 1023);
  int l = (int)((g >> 10) & 2047);
  int b = (int)(g >> 21);
  float s = bias[d];
  for (int i = 0; i < Pq; ++i) {
    if (l - i < 0) continue;
    const float* xr = x + ((size_t)b * Lq + (l - i)) * Dq;
    const float* wr = W + (size_t)d * Kq + i;
    float accv = 0.f;
    for (int dp = 0; dp < Dq; ++dp) accv += xr[dp] * wr[(size_t)dp * 4];
    s += accv;
  }
  out[g] = s;
}

extern "C" void kernel_launch(void* const* d_in, const int* in_sizes, int n_in,
                              void* d_out, int out_size, void* d_ws, size_t ws_size,
                              hipStream_t stream) {
  const float* x    = (const float*)d_in[0];
  const float* W    = (const float*)d_in[1];
  const float* bias = (const float*)d_in[2];
  float* out = (float*)d_out;

  const size_t WP_BYTES = (size_t)Dq * Kq * sizeof(unsigned short);        // 8 MiB
  const size_t XP_BYTES = (size_t)Bq * LPAD * Dq * sizeof(unsigned short); // ~33.7 MB

  if (ws_size < WP_BYTES + XP_BYTES) {
    const size_t total = (size_t)Bq * Lq * Dq;
    k_naive<<<(unsigned)((total + 255) / 256), 256, 0, stream>>>(x, W, bias, out);
    return;
  }

  unsigned short* Wp = (unsigned short*)d_ws;
  unsigned short* xp = (unsigned short*)((char*)d_ws + WP_BYTES);

  k_prep<<<10272, 256, 0, stream>>>(x, W, xp, Wp);
  k_gemm<<<dim3((Bq * Lq / BM) * (Dq / BN)), 512, 0, stream>>>(xp, Wp, bias, out);
}